// Round 2
// baseline (581.203 us; speedup 1.0000x reference)
//
#include <hip/hip_runtime.h>
#include <hip/hip_bf16.h>
#include <cstdint>

#define B_SZ 512
#define T_SZ 197
#define C_SZ 768
#define O_SZ 1000
#define K_SZ (C_SZ + C_SZ * 8)   // 6912 = base(768) + spline(6144)
#define NPAD 1024
#define LN_EPS 1e-5f

typedef __bf16 bf16;
typedef __bf16 bf16x4 __attribute__((ext_vector_type(4)));
typedef __bf16 bf16x8 __attribute__((ext_vector_type(8)));
typedef float  f32x4  __attribute__((ext_vector_type(4)));

// ---------------------------------------------------------------- kernel 0
// wmean[c] = (1/T) sum_t ln_weight[t,c]; bmean[c] = (1/T) sum_t ln_bias[t,c]
__global__ __launch_bounds__(256) void k0_wbmean(
    const float* __restrict__ lnw, const float* __restrict__ lnb,
    float* __restrict__ wmean, float* __restrict__ bmean)
{
    int c = blockIdx.x * 256 + threadIdx.x;
    if (c >= C_SZ) return;
    float sw = 0.f, sb = 0.f;
    for (int t = 0; t < T_SZ; ++t) {
        sw += lnw[t * C_SZ + c];
        sb += lnb[t * C_SZ + c];
    }
    const float invT = 1.0f / T_SZ;
    wmean[c] = sw * invT;
    bmean[c] = sb * invT;
}

// ---------------------------------------------------------------- kernel 2
// Wcat[o, k] bf16: k<768 -> base_weight[o,k]; else spline_weight[o,c,g]*scaler[o,c]
// rows o in [1000,1024) zeroed (N padding for the GEMM).
__global__ __launch_bounds__(256) void k2_prep_w(
    const float* __restrict__ bw, const float* __restrict__ sw,
    const float* __restrict__ ss, bf16* __restrict__ Wc)
{
    const int o = blockIdx.x;
    const int tid = threadIdx.x;
    bf16* row = Wc + (size_t)o * K_SZ;
    if (o >= O_SZ) {
        bf16x8 z = {};
        for (int i = tid; i < K_SZ / 8; i += 256)
            *(bf16x8*)(row + i * 8) = z;
        return;
    }
    for (int c = tid; c < C_SZ; c += 256)
        row[c] = (bf16)bw[(size_t)o * C_SZ + c];
    for (int c = tid; c < C_SZ; c += 256) {
        float sc = ss[(size_t)o * C_SZ + c];
        const float4* swp = (const float4*)(sw + ((size_t)o * C_SZ + c) * 8);
        float4 w0 = swp[0], w1 = swp[1];
        bf16x8 v;
        v[0] = (bf16)(w0.x * sc); v[1] = (bf16)(w0.y * sc);
        v[2] = (bf16)(w0.z * sc); v[3] = (bf16)(w0.w * sc);
        v[4] = (bf16)(w1.x * sc); v[5] = (bf16)(w1.y * sc);
        v[6] = (bf16)(w1.z * sc); v[7] = (bf16)(w1.w * sc);
        *(bf16x8*)(row + C_SZ + (size_t)c * 8) = v;
    }
}

// ---------------------------------------------------------------- kernel 1
// One pass over x[b]: accumulate S, S2 (LN stats) and A[c] = sum_t w[t,c]*x[b,t,c].
// Then pooled -> silu + cubic B-spline bases -> Act[b, 0..6912) in bf16.
__global__ __launch_bounds__(384) void k1_pool_feat(
    const float* __restrict__ x, const float* __restrict__ lnw,
    const float* __restrict__ wmean, const float* __restrict__ bmean,
    bf16* __restrict__ Act)
{
    const int b   = blockIdx.x;
    const int tid = threadIdx.x;
    const int u   = tid % 192;   // float4 column (4 channels)
    const int rg  = tid / 192;   // row-parity group

    const float4* X4 = (const float4*)(x + (size_t)b * T_SZ * C_SZ);
    const float4* W4 = (const float4*)lnw;

    float4 a4 = make_float4(0.f, 0.f, 0.f, 0.f);
    float s = 0.f, s2 = 0.f;
    for (int r = rg; r < T_SZ; r += 2) {
        float4 xv = X4[r * 192 + u];
        float4 wv = W4[r * 192 + u];
        a4.x += wv.x * xv.x; a4.y += wv.y * xv.y;
        a4.z += wv.z * xv.z; a4.w += wv.w * xv.w;
        s  += xv.x + xv.y + xv.z + xv.w;
        s2 += xv.x * xv.x + xv.y * xv.y + xv.z * xv.z + xv.w * xv.w;
    }
    // wave reduce (64-lane)
    for (int off = 32; off > 0; off >>= 1) {
        s  += __shfl_down(s,  off, 64);
        s2 += __shfl_down(s2, off, 64);
    }
    __shared__ float red_s[6], red_s2[6];
    __shared__ float4 aShare[192];
    __shared__ float stats[2];
    const int wave = tid >> 6, lane = tid & 63;
    if (lane == 0) { red_s[wave] = s; red_s2[wave] = s2; }
    if (rg == 1) aShare[u] = a4;
    __syncthreads();
    if (tid == 0) {
        float S = 0.f, S2 = 0.f;
        for (int i = 0; i < 6; ++i) { S += red_s[i]; S2 += red_s2[i]; }
        const float invN = 1.0f / (float)(T_SZ * C_SZ);
        float mean = S * invN;
        float var  = S2 * invN - mean * mean;   // biased, as in torch LayerNorm
        stats[0] = mean;
        stats[1] = rsqrtf(var + LN_EPS);
    }
    __syncthreads();
    if (rg == 0) {
        const float mean = stats[0], rstd = stats[1];
        float4 ao = aShare[u];
        a4.x += ao.x; a4.y += ao.y; a4.z += ao.z; a4.w += ao.w;
        const float invT = 1.0f / T_SZ;
        float p[4];
        bf16x4 basev;
        const float av[4] = { a4.x, a4.y, a4.z, a4.w };
        #pragma unroll
        for (int j = 0; j < 4; ++j) {
            int c = 4 * u + j;
            float pv = rstd * (av[j] * invT - mean * wmean[c]) + bmean[c];
            p[j] = pv;
            float si = pv / (1.f + expf(-pv));   // silu
            basev[j] = (bf16)si;
        }
        *(bf16x4*)(Act + (size_t)b * K_SZ + 4 * u) = basev;
        #pragma unroll
        for (int j = 0; j < 4; ++j) {
            float pv = p[j];
            float bas[11];
            #pragma unroll
            for (int i = 0; i < 11; ++i) {
                float g0 = (i - 3) * 0.4f - 1.0f;
                float g1 = (i - 2) * 0.4f - 1.0f;
                bas[i] = (pv >= g0 && pv < g1) ? 1.0f : 0.0f;
            }
            #pragma unroll
            for (int k = 1; k <= 3; ++k) {
                #pragma unroll
                for (int i = 0; i + k < 11; ++i) {
                    float gi   = (i - 3) * 0.4f - 1.0f;
                    float gik  = (i + k - 3) * 0.4f - 1.0f;
                    float gik1 = (i + k - 2) * 0.4f - 1.0f;
                    float gi1  = (i - 2) * 0.4f - 1.0f;
                    float left  = (pv - gi) / (gik - gi) * bas[i];
                    float right = (gik1 - pv) / (gik1 - gi1) * bas[i + 1];
                    bas[i] = left + right;
                }
            }
            bf16x8 sv;
            #pragma unroll
            for (int g = 0; g < 8; ++g) sv[g] = (bf16)bas[g];
            *(bf16x8*)(Act + (size_t)b * K_SZ + C_SZ + (size_t)(4 * u + j) * 8) = sv;
        }
    }
}

// ---------------------------------------------------------------- kernel 3
// Out[b,o] = sum_k Act[b,k] * Wc[o,k].  M=512, N=1024(pad), K=6912.
// 64x64 tile per block, 4 waves (2x2 of 32x32), BK=64, 16x16x32 bf16 MFMA.
// LDS rows padded to 72 bf16 (144 B = 9*16B, uint4-aligned) -> <=4-way aliasing.
__global__ __launch_bounds__(256) void k3_gemm(
    const bf16* __restrict__ Act, const bf16* __restrict__ Wc,
    float* __restrict__ Out)
{
    __shared__ __align__(16) bf16 As[64][72];
    __shared__ __align__(16) bf16 Bs[64][72];
    const int tid  = threadIdx.x;
    const int bm   = blockIdx.x & 7;    // 8 M-tiles
    const int bn   = blockIdx.x >> 3;   // 16 N-tiles
    const int m0   = bm * 64, n0 = bn * 64;
    const int wave = tid >> 6, lane = tid & 63;
    const int wr   = (wave >> 1) * 32, wc = (wave & 1) * 32;
    const int lr   = lane & 15, lk = (lane >> 4) * 8;

    f32x4 acc[2][2] = {};
    const int r0 = tid >> 3,          c0 = (tid & 7) * 8;
    const int r1 = (256 + tid) >> 3,  c1 = c0;   // second chunk, rows 32..63

    for (int k0 = 0; k0 < K_SZ; k0 += 64) {
        uint4 a0 = *(const uint4*)(Act + (size_t)(m0 + r0) * K_SZ + k0 + c0);
        uint4 a1 = *(const uint4*)(Act + (size_t)(m0 + r1) * K_SZ + k0 + c1);
        uint4 b0 = *(const uint4*)(Wc  + (size_t)(n0 + r0) * K_SZ + k0 + c0);
        uint4 b1 = *(const uint4*)(Wc  + (size_t)(n0 + r1) * K_SZ + k0 + c1);
        *(uint4*)(&As[r0][c0]) = a0;
        *(uint4*)(&As[r1][c1]) = a1;
        *(uint4*)(&Bs[r0][c0]) = b0;
        *(uint4*)(&Bs[r1][c1]) = b1;
        __syncthreads();
        #pragma unroll
        for (int kk = 0; kk < 64; kk += 32) {
            bf16x8 af[2], bfr[2];
            #pragma unroll
            for (int mi = 0; mi < 2; ++mi)
                af[mi] = *(const bf16x8*)(&As[wr + mi * 16 + lr][kk + lk]);
            #pragma unroll
            for (int ni = 0; ni < 2; ++ni)
                bfr[ni] = *(const bf16x8*)(&Bs[wc + ni * 16 + lr][kk + lk]);
            #pragma unroll
            for (int mi = 0; mi < 2; ++mi)
                #pragma unroll
                for (int ni = 0; ni < 2; ++ni)
                    acc[mi][ni] = __builtin_amdgcn_mfma_f32_16x16x32_bf16(
                        af[mi], bfr[ni], acc[mi][ni], 0, 0, 0);
        }
        __syncthreads();
    }
    #pragma unroll
    for (int mi = 0; mi < 2; ++mi)
        #pragma unroll
        for (int ni = 0; ni < 2; ++ni) {
            int col = n0 + wc + ni * 16 + lr;
            if (col < O_SZ) {
                #pragma unroll
                for (int j = 0; j < 4; ++j) {
                    int rowi = m0 + wr + mi * 16 + (lane >> 4) * 4 + j;
                    Out[(size_t)rowi * O_SZ + col] = acc[mi][ni][j];
                }
            }
        }
}

// ---------------------------------------------------------------- launch
extern "C" void kernel_launch(void* const* d_in, const int* in_sizes, int n_in,
                              void* d_out, int out_size, void* d_ws, size_t ws_size,
                              hipStream_t stream)
{
    const float* x   = (const float*)d_in[0];
    const float* lnw = (const float*)d_in[1];
    const float* lnb = (const float*)d_in[2];
    const float* bw  = (const float*)d_in[3];
    const float* sw  = (const float*)d_in[4];
    const float* ss  = (const float*)d_in[5];
    float* Out = (float*)d_out;

    char* ws = (char*)d_ws;
    float* wmean = (float*)ws;                       // 768 f32
    float* bmean = wmean + C_SZ;                     // 768 f32
    bf16*  Act   = (bf16*)(ws + 8192);               // 512 x 6912 bf16 (~7.1 MB)
    bf16*  Wcat  = (bf16*)(ws + 8192 + (size_t)B_SZ * K_SZ * 2);  // 1024 x 6912 bf16 (~14.2 MB)

    k0_wbmean<<<3, 256, 0, stream>>>(lnw, lnb, wmean, bmean);
    k2_prep_w<<<NPAD, 256, 0, stream>>>(bw, sw, ss, Wcat);
    k1_pool_feat<<<B_SZ, 384, 0, stream>>>(x, lnw, wmean, bmean, Act);
    k3_gemm<<<128, 256, 0, stream>>>(Act, Wcat, Out);
}

// Round 4
// 524.096 us; speedup vs baseline: 1.1090x; 1.1090x over previous
//
#include <hip/hip_runtime.h>
#include <hip/hip_bf16.h>
#include <cstdint>

#define B_SZ 512
#define T_SZ 197
#define C_SZ 768
#define O_SZ 1000
#define K_SZ (C_SZ + C_SZ * 8)   // 6912 = base(768) + spline(6144)
#define NPAD 1024
#define LN_EPS 1e-5f

typedef __bf16 bf16;
typedef __bf16 bf16x4 __attribute__((ext_vector_type(4)));
typedef __bf16 bf16x8 __attribute__((ext_vector_type(8)));
typedef float  f32x4  __attribute__((ext_vector_type(4)));

// ---------------------------------------------------------------- kernel 0
// wmean[c] = (1/T) sum_t ln_weight[t,c]; bmean[c] = (1/T) sum_t ln_bias[t,c]
// 24 blocks x 256 thr: 32 channels/block, 8 threads/channel (t strided), LDS reduce.
__global__ __launch_bounds__(256) void k0_wbmean(
    const float* __restrict__ lnw, const float* __restrict__ lnb,
    float* __restrict__ wmean, float* __restrict__ bmean)
{
    const int tid  = threadIdx.x;
    const int cl   = tid & 31;
    const int c    = blockIdx.x * 32 + cl;
    const int tsub = tid >> 5;          // 0..7
    float sw = 0.f, sb = 0.f;
    for (int t = tsub; t < T_SZ; t += 8) {
        sw += lnw[t * C_SZ + c];
        sb += lnb[t * C_SZ + c];
    }
    __shared__ float rs[8][32], rb[8][32];
    rs[tsub][cl] = sw;
    rb[tsub][cl] = sb;
    __syncthreads();
    if (tsub == 0) {
        float SW = 0.f, SB = 0.f;
        #pragma unroll
        for (int i = 0; i < 8; ++i) { SW += rs[i][cl]; SB += rb[i][cl]; }
        const float invT = 1.0f / T_SZ;
        wmean[c] = SW * invT;
        bmean[c] = SB * invT;
    }
}

// ---------------------------------------------------------------- zero Out
// 512*1000 floats = 128000 float4 = 500 blocks x 256 threads exactly.
__global__ __launch_bounds__(256) void kz_zero(float4* __restrict__ out)
{
    out[blockIdx.x * 256 + threadIdx.x] = make_float4(0.f, 0.f, 0.f, 0.f);
}

// ---------------------------------------------------------------- kernel 2
// Wcat[o, k] bf16: k<768 -> base_weight[o,k]; else spline_weight[o,c,g]*scaler[o,c]
// rows o in [1000,1024) zeroed (N padding for the GEMM).
__global__ __launch_bounds__(256) void k2_prep_w(
    const float* __restrict__ bw, const float* __restrict__ sw,
    const float* __restrict__ ss, bf16* __restrict__ Wc)
{
    const int o = blockIdx.x;
    const int tid = threadIdx.x;
    bf16* row = Wc + (size_t)o * K_SZ;
    if (o >= O_SZ) {
        bf16x8 z = {};
        for (int i = tid; i < K_SZ / 8; i += 256)
            *(bf16x8*)(row + i * 8) = z;
        return;
    }
    for (int c = tid; c < C_SZ; c += 256)
        row[c] = (bf16)bw[(size_t)o * C_SZ + c];
    for (int c = tid; c < C_SZ; c += 256) {
        float sc = ss[(size_t)o * C_SZ + c];
        const float4* swp = (const float4*)(sw + ((size_t)o * C_SZ + c) * 8);
        float4 w0 = swp[0], w1 = swp[1];
        bf16x8 v;
        v[0] = (bf16)(w0.x * sc); v[1] = (bf16)(w0.y * sc);
        v[2] = (bf16)(w0.z * sc); v[3] = (bf16)(w0.w * sc);
        v[4] = (bf16)(w1.x * sc); v[5] = (bf16)(w1.y * sc);
        v[6] = (bf16)(w1.z * sc); v[7] = (bf16)(w1.w * sc);
        *(bf16x8*)(row + C_SZ + (size_t)c * 8) = v;
    }
}

// ---------------------------------------------------------------- kernel 1
// One pass over x[b]: accumulate S, S2 (LN stats) and A[c] = sum_t w[t,c]*x[b,t,c].
// Then pooled -> silu + cubic B-spline bases -> Act[b, 0..6912) in bf16.
__global__ __launch_bounds__(384) void k1_pool_feat(
    const float* __restrict__ x, const float* __restrict__ lnw,
    const float* __restrict__ wmean, const float* __restrict__ bmean,
    bf16* __restrict__ Act)
{
    const int b   = blockIdx.x;
    const int tid = threadIdx.x;
    const int u   = tid % 192;   // float4 column (4 channels)
    const int rg  = tid / 192;   // row-parity group

    const float4* X4 = (const float4*)(x + (size_t)b * T_SZ * C_SZ);
    const float4* W4 = (const float4*)lnw;

    float4 a4 = make_float4(0.f, 0.f, 0.f, 0.f);
    float s = 0.f, s2 = 0.f;
    for (int r = rg; r < T_SZ; r += 2) {
        float4 xv = X4[r * 192 + u];
        float4 wv = W4[r * 192 + u];
        a4.x += wv.x * xv.x; a4.y += wv.y * xv.y;
        a4.z += wv.z * xv.z; a4.w += wv.w * xv.w;
        s  += xv.x + xv.y + xv.z + xv.w;
        s2 += xv.x * xv.x + xv.y * xv.y + xv.z * xv.z + xv.w * xv.w;
    }
    // wave reduce (64-lane)
    for (int off = 32; off > 0; off >>= 1) {
        s  += __shfl_down(s,  off, 64);
        s2 += __shfl_down(s2, off, 64);
    }
    __shared__ float red_s[6], red_s2[6];
    __shared__ float4 aShare[192];
    __shared__ float stats[2];
    const int wave = tid >> 6, lane = tid & 63;
    if (lane == 0) { red_s[wave] = s; red_s2[wave] = s2; }
    if (rg == 1) aShare[u] = a4;
    __syncthreads();
    if (tid == 0) {
        float S = 0.f, S2 = 0.f;
        for (int i = 0; i < 6; ++i) { S += red_s[i]; S2 += red_s2[i]; }
        const float invN = 1.0f / (float)(T_SZ * C_SZ);
        float mean = S * invN;
        float var  = S2 * invN - mean * mean;   // biased, as in torch LayerNorm
        stats[0] = mean;
        stats[1] = rsqrtf(var + LN_EPS);
    }
    __syncthreads();
    if (rg == 0) {
        const float mean = stats[0], rstd = stats[1];
        float4 ao = aShare[u];
        a4.x += ao.x; a4.y += ao.y; a4.z += ao.z; a4.w += ao.w;
        const float invT = 1.0f / T_SZ;
        float p[4];
        bf16x4 basev;
        const float av[4] = { a4.x, a4.y, a4.z, a4.w };
        #pragma unroll
        for (int j = 0; j < 4; ++j) {
            int c = 4 * u + j;
            float pv = rstd * (av[j] * invT - mean * wmean[c]) + bmean[c];
            p[j] = pv;
            float si = pv / (1.f + expf(-pv));   // silu
            basev[j] = (bf16)si;
        }
        *(bf16x4*)(Act + (size_t)b * K_SZ + 4 * u) = basev;
        #pragma unroll
        for (int j = 0; j < 4; ++j) {
            float pv = p[j];
            float bas[11];
            #pragma unroll
            for (int i = 0; i < 11; ++i) {
                float g0 = (i - 3) * 0.4f - 1.0f;
                float g1 = (i - 2) * 0.4f - 1.0f;
                bas[i] = (pv >= g0 && pv < g1) ? 1.0f : 0.0f;
            }
            #pragma unroll
            for (int k = 1; k <= 3; ++k) {
                #pragma unroll
                for (int i = 0; i + k < 11; ++i) {
                    float gi   = (i - 3) * 0.4f - 1.0f;
                    float gik  = (i + k - 3) * 0.4f - 1.0f;
                    float gik1 = (i + k - 2) * 0.4f - 1.0f;
                    float gi1  = (i - 2) * 0.4f - 1.0f;
                    float left  = (pv - gi) / (gik - gi) * bas[i];
                    float right = (gik1 - pv) / (gik1 - gi1) * bas[i + 1];
                    bas[i] = left + right;
                }
            }
            bf16x8 sv;
            #pragma unroll
            for (int g = 0; g < 8; ++g) sv[g] = (bf16)bas[g];
            *(bf16x8*)(Act + (size_t)b * K_SZ + C_SZ + (size_t)(4 * u + j) * 8) = sv;
        }
    }
}

// ---------------------------------------------------------------- kernel 3
// Out[b,o] += sum_k Act[b,k] * Wc[o,k].  M=512, N=1024(pad), K=6912, split-K x2.
// 256 blocks: low 7 bits = tile (8 M x 16 N), bit 7 = K-half. 64x64 tile,
// 4 waves (2x2 of 32x32), BK=64, 16x16x32 bf16 MFMA. LDS rows padded to 72
// bf16 (144 B) -> <=2-way bank aliasing (free per m136). Epilogue: f32
// global atomic add (native) into zero-initialized Out.
__global__ __launch_bounds__(256) void k3_gemm(
    const bf16* __restrict__ Act, const bf16* __restrict__ Wc,
    float* __restrict__ Out)
{
    __shared__ __align__(16) bf16 As[64][72];
    __shared__ __align__(16) bf16 Bs[64][72];
    const int tid  = threadIdx.x;
    const int tile = blockIdx.x & 127;
    const int ks   = blockIdx.x >> 7;        // K-half
    const int bm   = tile & 7;               // 8 M-tiles
    const int bn   = tile >> 3;              // 16 N-tiles
    const int m0   = bm * 64, n0 = bn * 64;
    const int kbeg = ks * (K_SZ / 2), kend = kbeg + K_SZ / 2;   // 3456 each, 54 iters
    const int wave = tid >> 6, lane = tid & 63;
    const int wr   = (wave >> 1) * 32, wc = (wave & 1) * 32;
    const int lr   = lane & 15, lk = (lane >> 4) * 8;

    f32x4 acc[2][2] = {};
    const int r0 = tid >> 3,          c0 = (tid & 7) * 8;
    const int r1 = (256 + tid) >> 3,  c1 = c0;   // second chunk, rows 32..63

    for (int k0 = kbeg; k0 < kend; k0 += 64) {
        uint4 a0 = *(const uint4*)(Act + (size_t)(m0 + r0) * K_SZ + k0 + c0);
        uint4 a1 = *(const uint4*)(Act + (size_t)(m0 + r1) * K_SZ + k0 + c1);
        uint4 b0 = *(const uint4*)(Wc  + (size_t)(n0 + r0) * K_SZ + k0 + c0);
        uint4 b1 = *(const uint4*)(Wc  + (size_t)(n0 + r1) * K_SZ + k0 + c1);
        *(uint4*)(&As[r0][c0]) = a0;
        *(uint4*)(&As[r1][c1]) = a1;
        *(uint4*)(&Bs[r0][c0]) = b0;
        *(uint4*)(&Bs[r1][c1]) = b1;
        __syncthreads();
        #pragma unroll
        for (int kk = 0; kk < 64; kk += 32) {
            bf16x8 af[2], bfr[2];
            #pragma unroll
            for (int mi = 0; mi < 2; ++mi)
                af[mi] = *(const bf16x8*)(&As[wr + mi * 16 + lr][kk + lk]);
            #pragma unroll
            for (int ni = 0; ni < 2; ++ni)
                bfr[ni] = *(const bf16x8*)(&Bs[wc + ni * 16 + lr][kk + lk]);
            #pragma unroll
            for (int mi = 0; mi < 2; ++mi)
                #pragma unroll
                for (int ni = 0; ni < 2; ++ni)
                    acc[mi][ni] = __builtin_amdgcn_mfma_f32_16x16x32_bf16(
                        af[mi], bfr[ni], acc[mi][ni], 0, 0, 0);
        }
        __syncthreads();
    }
    #pragma unroll
    for (int mi = 0; mi < 2; ++mi)
        #pragma unroll
        for (int ni = 0; ni < 2; ++ni) {
            int col = n0 + wc + ni * 16 + lr;
            if (col < O_SZ) {
                #pragma unroll
                for (int j = 0; j < 4; ++j) {
                    int rowi = m0 + wr + mi * 16 + (lane >> 4) * 4 + j;
                    unsafeAtomicAdd(&Out[(size_t)rowi * O_SZ + col], acc[mi][ni][j]);
                }
            }
        }
}

// ---------------------------------------------------------------- launch
extern "C" void kernel_launch(void* const* d_in, const int* in_sizes, int n_in,
                              void* d_out, int out_size, void* d_ws, size_t ws_size,
                              hipStream_t stream)
{
    const float* x   = (const float*)d_in[0];
    const float* lnw = (const float*)d_in[1];
    const float* lnb = (const float*)d_in[2];
    const float* bw  = (const float*)d_in[3];
    const float* sw  = (const float*)d_in[4];
    const float* ss  = (const float*)d_in[5];
    float* Out = (float*)d_out;

    char* ws = (char*)d_ws;
    float* wmean = (float*)ws;                       // 768 f32
    float* bmean = wmean + C_SZ;                     // 768 f32
    bf16*  Act   = (bf16*)(ws + 8192);               // 512 x 6912 bf16 (~7.1 MB)
    bf16*  Wcat  = (bf16*)(ws + 8192 + (size_t)B_SZ * K_SZ * 2);  // 1024 x 6912 bf16 (~14.2 MB)

    k0_wbmean<<<24, 256, 0, stream>>>(lnw, lnb, wmean, bmean);
    kz_zero<<<500, 256, 0, stream>>>((float4*)Out);
    k2_prep_w<<<NPAD, 256, 0, stream>>>(bw, sw, ss, Wcat);
    k1_pool_feat<<<B_SZ, 384, 0, stream>>>(x, lnw, wmean, bmean, Act);
    k3_gemm<<<256, 256, 0, stream>>>(Act, Wcat, Out);
}

// Round 5
// 495.701 us; speedup vs baseline: 1.1725x; 1.0573x over previous
//
#include <hip/hip_runtime.h>
#include <hip/hip_bf16.h>
#include <cstdint>

#define B_SZ 512
#define T_SZ 197
#define C_SZ 768
#define O_SZ 1000
#define K_SZ (C_SZ + C_SZ * 8)   // 6912 = base(768) + spline(6144)
#define NPAD 1024
#define LN_EPS 1e-5f

typedef __bf16 bf16;
typedef __bf16 bf16x4 __attribute__((ext_vector_type(4)));
typedef __bf16 bf16x8 __attribute__((ext_vector_type(8)));
typedef float  f32x4  __attribute__((ext_vector_type(4)));

__device__ __forceinline__ void gload_lds16(const void* g, void* l) {
    __builtin_amdgcn_global_load_lds(
        (const __attribute__((address_space(1))) unsigned int*)g,
        (__attribute__((address_space(3))) unsigned int*)l, 16, 0, 0);
}

// ---------------------------------------------------------------- kernel 0
// Fused: zero Out (500*256 float4 = 512*1000 floats exactly) + wmean/bmean
// on blocks 0..23 (32 channels/block, 8 threads/channel, LDS reduce).
__global__ __launch_bounds__(256) void k0_wbz(
    const float* __restrict__ lnw, const float* __restrict__ lnb,
    float* __restrict__ wmean, float* __restrict__ bmean,
    float4* __restrict__ out)
{
    const int tid = threadIdx.x;
    out[blockIdx.x * 256 + tid] = make_float4(0.f, 0.f, 0.f, 0.f);
    if (blockIdx.x < 24) {
        const int cl   = tid & 31;
        const int c    = blockIdx.x * 32 + cl;
        const int tsub = tid >> 5;          // 0..7
        float sw = 0.f, sb = 0.f;
        for (int t = tsub; t < T_SZ; t += 8) {
            sw += lnw[t * C_SZ + c];
            sb += lnb[t * C_SZ + c];
        }
        __shared__ float rs[8][32], rb[8][32];
        rs[tsub][cl] = sw;
        rb[tsub][cl] = sb;
        __syncthreads();
        if (tsub == 0) {
            float SW = 0.f, SB = 0.f;
            #pragma unroll
            for (int i = 0; i < 8; ++i) { SW += rs[i][cl]; SB += rb[i][cl]; }
            const float invT = 1.0f / T_SZ;
            wmean[c] = SW * invT;
            bmean[c] = SB * invT;
        }
    }
}

// ---------------------------------------------------------------- kernel 2
// Wcat[o, k] bf16: k<768 -> base_weight[o,k]; else spline_weight[o,c,g]*scaler[o,c]
// rows o in [1000,1024) zeroed (N padding for the GEMM).
__global__ __launch_bounds__(256) void k2_prep_w(
    const float* __restrict__ bw, const float* __restrict__ sw,
    const float* __restrict__ ss, bf16* __restrict__ Wc)
{
    const int o = blockIdx.x;
    const int tid = threadIdx.x;
    bf16* row = Wc + (size_t)o * K_SZ;
    if (o >= O_SZ) {
        bf16x8 z = {};
        for (int i = tid; i < K_SZ / 8; i += 256)
            *(bf16x8*)(row + i * 8) = z;
        return;
    }
    for (int c = tid; c < C_SZ; c += 256)
        row[c] = (bf16)bw[(size_t)o * C_SZ + c];
    for (int c = tid; c < C_SZ; c += 256) {
        float sc = ss[(size_t)o * C_SZ + c];
        const float4* swp = (const float4*)(sw + ((size_t)o * C_SZ + c) * 8);
        float4 w0 = swp[0], w1 = swp[1];
        bf16x8 v;
        v[0] = (bf16)(w0.x * sc); v[1] = (bf16)(w0.y * sc);
        v[2] = (bf16)(w0.z * sc); v[3] = (bf16)(w0.w * sc);
        v[4] = (bf16)(w1.x * sc); v[5] = (bf16)(w1.y * sc);
        v[6] = (bf16)(w1.z * sc); v[7] = (bf16)(w1.w * sc);
        *(bf16x8*)(row + C_SZ + (size_t)c * 8) = v;
    }
}

// ---------------------------------------------------------------- kernel 1
// One pass over x[b]: accumulate S, S2 (LN stats) and A[c] = sum_t w[t,c]*x[b,t,c].
// Then pooled -> silu + cubic B-spline bases -> Act[b, 0..6912) in bf16.
// 768 thr/block (12 waves) x 512 blocks = 24 waves/CU (was 12: grid-limited).
__global__ __launch_bounds__(768) void k1_pool_feat(
    const float* __restrict__ x, const float* __restrict__ lnw,
    const float* __restrict__ wmean, const float* __restrict__ bmean,
    bf16* __restrict__ Act)
{
    const int b   = blockIdx.x;
    const int tid = threadIdx.x;
    const int u   = tid % 192;   // float4 column (4 channels)
    const int rg  = tid / 192;   // row group 0..3

    const float4* X4 = (const float4*)(x + (size_t)b * T_SZ * C_SZ);
    const float4* W4 = (const float4*)lnw;

    float4 a4 = make_float4(0.f, 0.f, 0.f, 0.f);
    float s = 0.f, s2 = 0.f;
    for (int r = rg; r < T_SZ; r += 4) {
        float4 xv = X4[r * 192 + u];
        float4 wv = W4[r * 192 + u];
        a4.x += wv.x * xv.x; a4.y += wv.y * xv.y;
        a4.z += wv.z * xv.z; a4.w += wv.w * xv.w;
        s  += xv.x + xv.y + xv.z + xv.w;
        s2 += xv.x * xv.x + xv.y * xv.y + xv.z * xv.z + xv.w * xv.w;
    }
    // wave reduce (64-lane)
    for (int off = 32; off > 0; off >>= 1) {
        s  += __shfl_down(s,  off, 64);
        s2 += __shfl_down(s2, off, 64);
    }
    __shared__ float red_s[12], red_s2[12];
    __shared__ float4 aShare[3][192];
    __shared__ float stats[2];
    const int wave = tid >> 6, lane = tid & 63;
    if (lane == 0) { red_s[wave] = s; red_s2[wave] = s2; }
    if (rg >= 1) aShare[rg - 1][u] = a4;
    __syncthreads();
    if (tid == 0) {
        float S = 0.f, S2 = 0.f;
        for (int i = 0; i < 12; ++i) { S += red_s[i]; S2 += red_s2[i]; }
        const float invN = 1.0f / (float)(T_SZ * C_SZ);
        float mean = S * invN;
        float var  = S2 * invN - mean * mean;   // biased, as in torch LayerNorm
        stats[0] = mean;
        stats[1] = rsqrtf(var + LN_EPS);
    }
    __syncthreads();
    if (rg == 0) {
        const float mean = stats[0], rstd = stats[1];
        #pragma unroll
        for (int g = 0; g < 3; ++g) {
            float4 ao = aShare[g][u];
            a4.x += ao.x; a4.y += ao.y; a4.z += ao.z; a4.w += ao.w;
        }
        const float invT = 1.0f / T_SZ;
        float p[4];
        bf16x4 basev;
        const float av[4] = { a4.x, a4.y, a4.z, a4.w };
        #pragma unroll
        for (int j = 0; j < 4; ++j) {
            int c = 4 * u + j;
            float pv = rstd * (av[j] * invT - mean * wmean[c]) + bmean[c];
            p[j] = pv;
            float si = pv / (1.f + expf(-pv));   // silu
            basev[j] = (bf16)si;
        }
        *(bf16x4*)(Act + (size_t)b * K_SZ + 4 * u) = basev;
        #pragma unroll
        for (int j = 0; j < 4; ++j) {
            float pv = p[j];
            float bas[11];
            #pragma unroll
            for (int i = 0; i < 11; ++i) {
                float g0 = (i - 3) * 0.4f - 1.0f;
                float g1 = (i - 2) * 0.4f - 1.0f;
                bas[i] = (pv >= g0 && pv < g1) ? 1.0f : 0.0f;
            }
            #pragma unroll
            for (int k = 1; k <= 3; ++k) {
                #pragma unroll
                for (int i = 0; i + k < 11; ++i) {
                    float gi   = (i - 3) * 0.4f - 1.0f;
                    float gik  = (i + k - 3) * 0.4f - 1.0f;
                    float gik1 = (i + k - 2) * 0.4f - 1.0f;
                    float gi1  = (i - 2) * 0.4f - 1.0f;
                    float left  = (pv - gi) / (gik - gi) * bas[i];
                    float right = (gik1 - pv) / (gik1 - gi1) * bas[i + 1];
                    bas[i] = left + right;
                }
            }
            bf16x8 sv;
            #pragma unroll
            for (int g = 0; g < 8; ++g) sv[g] = (bf16)bas[g];
            *(bf16x8*)(Act + (size_t)b * K_SZ + C_SZ + (size_t)(4 * u + j) * 8) = sv;
        }
    }
}

// ---------------------------------------------------------------- kernel 3
// Out[b,o] += sum_k Act[b,k] * Wc[o,k].  M=512, N=1024(pad), K=6912, split-K x4.
// 512 blocks (2/CU): low 7 bits = tile (8M x 16N), high 2 = K-quarter (27 BK=64
// tiles each). T3-minimum 2-phase: global_load_lds width-16 direct staging into
// double-buffered linear LDS [64][64] bf16, 1 tile prefetch ahead, one
// drain+barrier per tile. Rule-21 involution swizzle: source granule col8 ^=
// (row&7) at stage, ds_read addr ^= ((row&7)<<4) -> near-conflict-free b128.
__global__ __launch_bounds__(256) void k3_gemm(
    const bf16* __restrict__ Act, const bf16* __restrict__ Wc,
    float* __restrict__ Out)
{
    __shared__ __align__(16) char lds[2][16384];   // [buf][ A:0..8191 | B:8192..16383 ]
    const int tid  = threadIdx.x;
    const int tile = blockIdx.x & 127;
    const int ks   = blockIdx.x >> 7;        // K-quarter 0..3
    const int bm   = tile & 7;               // 8 M-tiles
    const int bn   = tile >> 3;              // 16 N-tiles
    const int m0   = bm * 64, n0 = bn * 64;
    const int kbeg = ks * (K_SZ / 4), kend = kbeg + K_SZ / 4;   // 1728 each, 27 tiles
    const int wave = tid >> 6, lane = tid & 63;
    const int wr   = (wave >> 1) * 32, wc = (wave & 1) * 32;
    const int lr   = lane & 15, lq = lane >> 4;

    // staging geometry: granule g=tid -> row=g>>3 (0..31), g=tid+256 -> row+32.
    // (row+32)&7 == row&7, so the source swizzle col is shared by both passes.
    const int srow = tid >> 3;
    const int scol = (((tid & 7) ^ (srow & 7)) << 3);   // swizzled col (elements)
    const size_t aoff = (size_t)(m0 + srow) * K_SZ + scol;
    const size_t boff = (size_t)(n0 + srow) * K_SZ + scol;
    char* const lwb = lds[0] + (wave << 10);            // wave-uniform LDS base, buf 0

    f32x4 acc[2][2] = {};

    #define STAGE(buf, kk0)  do {                                              \
        char* lb_ = lwb + (buf) * 16384;                                       \
        gload_lds16(Act + aoff + (kk0), lb_);                                  \
        gload_lds16(Act + aoff + (size_t)32 * K_SZ + (kk0), lb_ + 4096);       \
        gload_lds16(Wc  + boff + (kk0), lb_ + 8192);                           \
        gload_lds16(Wc  + boff + (size_t)32 * K_SZ + (kk0), lb_ + 12288);      \
    } while (0)

    STAGE(0, kbeg);
    __syncthreads();                          // drains vmcnt(0): tile 0 staged
    int cur = 0;
    for (int k0 = kbeg; k0 < kend; k0 += 64) {
        if (k0 + 64 < kend) STAGE(cur ^ 1, k0 + 64);   // prefetch next tile
        const char* la = lds[cur];
        const char* lbm = lds[cur] + 8192;
        #pragma unroll
        for (int kk = 0; kk < 64; kk += 32) {
            const int sbase = (kk >> 3) + lq;          // granule slot 0..7
            bf16x8 af[2], bfr[2];
            #pragma unroll
            for (int mi = 0; mi < 2; ++mi) {
                int row = wr + mi * 16 + lr;
                af[mi] = *(const bf16x8*)(la + row * 128 + ((sbase ^ (row & 7)) << 4));
            }
            #pragma unroll
            for (int ni = 0; ni < 2; ++ni) {
                int row = wc + ni * 16 + lr;
                bfr[ni] = *(const bf16x8*)(lbm + row * 128 + ((sbase ^ (row & 7)) << 4));
            }
            #pragma unroll
            for (int mi = 0; mi < 2; ++mi)
                #pragma unroll
                for (int ni = 0; ni < 2; ++ni)
                    acc[mi][ni] = __builtin_amdgcn_mfma_f32_16x16x32_bf16(
                        af[mi], bfr[ni], acc[mi][ni], 0, 0, 0);
        }
        __syncthreads();                      // drains prefetch; next tile ready
        cur ^= 1;
    }
    #undef STAGE

    #pragma unroll
    for (int mi = 0; mi < 2; ++mi)
        #pragma unroll
        for (int ni = 0; ni < 2; ++ni) {
            int col = n0 + wc + ni * 16 + lr;
            if (col < O_SZ) {
                #pragma unroll
                for (int j = 0; j < 4; ++j) {
                    int rowi = m0 + wr + mi * 16 + lq * 4 + j;
                    unsafeAtomicAdd(&Out[(size_t)rowi * O_SZ + col], acc[mi][ni][j]);
                }
            }
        }
}

// ---------------------------------------------------------------- launch
extern "C" void kernel_launch(void* const* d_in, const int* in_sizes, int n_in,
                              void* d_out, int out_size, void* d_ws, size_t ws_size,
                              hipStream_t stream)
{
    const float* x   = (const float*)d_in[0];
    const float* lnw = (const float*)d_in[1];
    const float* lnb = (const float*)d_in[2];
    const float* bw  = (const float*)d_in[3];
    const float* sw  = (const float*)d_in[4];
    const float* ss  = (const float*)d_in[5];
    float* Out = (float*)d_out;

    char* ws = (char*)d_ws;
    float* wmean = (float*)ws;                       // 768 f32
    float* bmean = wmean + C_SZ;                     // 768 f32
    bf16*  Act   = (bf16*)(ws + 8192);               // 512 x 6912 bf16 (~7.1 MB)
    bf16*  Wcat  = (bf16*)(ws + 8192 + (size_t)B_SZ * K_SZ * 2);  // 1024 x 6912 bf16 (~14.2 MB)

    k0_wbz<<<500, 256, 0, stream>>>(lnw, lnb, wmean, bmean, (float4*)Out);
    k2_prep_w<<<NPAD, 256, 0, stream>>>(bw, sw, ss, Wcat);
    k1_pool_feat<<<B_SZ, 768, 0, stream>>>(x, lnw, wmean, bmean, Act);
    k3_gemm<<<512, 256, 0, stream>>>(Act, Wcat, Out);
}